// Round 3
// baseline (1313.632 us; speedup 1.0000x reference)
//
#include <hip/hip_runtime.h>
#include <math.h>

// Problem constants (S=8192 tokens, E=64 experts, capacity=256)
#define NTOK 8192
#define NEXP 64
#define CAP  256
#define SEC  (NTOK * NEXP * CAP)   // 134217728 floats per output tensor

typedef float v4f __attribute__((ext_vector_type(4)));

// ---------------------------------------------------------------------------
// Kernel 1: per-token argmax (first-index tie-break) + softmax value at top1.
// One wave (64 lanes) per token row; lane e holds logit for expert e.
// ---------------------------------------------------------------------------
__global__ __launch_bounds__(256) void k_top1(const float* __restrict__ in,
                                              int* __restrict__ top1,
                                              float* __restrict__ val) {
    int wave = threadIdx.x >> 6;
    int lane = threadIdx.x & 63;
    int s = blockIdx.x * 4 + wave;
    float x = in[s * NEXP + lane];

    float bv = x;
    int   bi = lane;
#pragma unroll
    for (int off = 32; off > 0; off >>= 1) {
        float ov = __shfl_xor(bv, off);
        int   oi = __shfl_xor(bi, off);
        if (ov > bv || (ov == bv && oi < bi)) { bv = ov; bi = oi; }
    }
    float ex = expf(x - bv);
#pragma unroll
    for (int off = 32; off > 0; off >>= 1) ex += __shfl_xor(ex, off);

    if (lane == 0) {
        top1[s] = bi;
        val[s]  = 1.0f / ex;   // softmax value at the argmax
    }
}

// ---------------------------------------------------------------------------
// Kernel 2: deterministic per-expert exclusive rank via 6-ballot radix masks.
// Single block, 16 waves; wave w owns tokens [w*512, w*512+512).
// No loop-carried cross-lane chains: per 64-token batch, 6 ballots give every
// lane (a) the mask of lanes sharing ITS expert (in-batch rank) and (b) the
// batch count for expert==lane (register histogram update).
// Emits packed rowinfo: {pos = t*CAP + rank (or -1 if dropped), bits(val)}.
// ---------------------------------------------------------------------------
__global__ __launch_bounds__(1024) void k_rank(const int* __restrict__ top1,
                                               const float* __restrict__ val,
                                               int2* __restrict__ rowinfo) {
    __shared__ int localrank[NTOK];      // 32 KB
    __shared__ int hist[16][64];
    __shared__ int chunkoff[16][64];

    int tid  = threadIdx.x;
    int w    = tid >> 6;
    int lane = tid & 63;
    int base = w * 512;

    int cnt = 0;  // lane l: tokens so far in this chunk routed to expert l
    for (int j0 = 0; j0 < 512; j0 += 64) {
        int e = top1[base + j0 + lane];
        unsigned long long b0 = __ballot((e & 1)  != 0);
        unsigned long long b1 = __ballot((e & 2)  != 0);
        unsigned long long b2 = __ballot((e & 4)  != 0);
        unsigned long long b3 = __ballot((e & 8)  != 0);
        unsigned long long b4 = __ballot((e & 16) != 0);
        unsigned long long b5 = __ballot((e & 32) != 0);
        // lanes whose expert == my expert
        unsigned long long my =
            ((e & 1)  ? b0 : ~b0) & ((e & 2)  ? b1 : ~b1) &
            ((e & 4)  ? b2 : ~b2) & ((e & 8)  ? b3 : ~b3) &
            ((e & 16) ? b4 : ~b4) & ((e & 32) ? b5 : ~b5);
        // lanes whose expert == `lane` (for the register histogram)
        unsigned long long mb =
            ((lane & 1)  ? b0 : ~b0) & ((lane & 2)  ? b1 : ~b1) &
            ((lane & 4)  ? b2 : ~b2) & ((lane & 8)  ? b3 : ~b3) &
            ((lane & 16) ? b4 : ~b4) & ((lane & 32) ? b5 : ~b5);

        int lr  = __popcll(my & ((1ULL << lane) - 1ULL));  // rank within batch
        int off = __shfl(cnt, e);                           // earlier batches, same expert
        localrank[base + j0 + lane] = off + lr;
        cnt += __popcll(mb);
    }
    hist[w][lane] = cnt;
    __syncthreads();

    if (tid < 64) {  // lane-per-expert exclusive scan over 16 chunks
        int off = 0;
        for (int w2 = 0; w2 < 16; ++w2) {
            chunkoff[w2][tid] = off;
            off += hist[w2][tid];
        }
    }
    __syncthreads();

    for (int s = tid; s < NTOK; s += 1024) {
        int t = top1[s];
        int r = localrank[s] + chunkoff[s >> 9][t];
        int pos = (r < CAP) ? (t * CAP + r) : -1;   // -1: dropped token, row all-zero
        rowinfo[s] = make_int2(pos, __float_as_int(val[s]));
    }
}

// ---------------------------------------------------------------------------
// Kernel 3: fused zero-fill + scatter. Each thread writes 2 float4 into EACH
// output (64 B/thread). One broadcast 8B rowinfo load per thread; 1 GiB of
// nontemporal dwordx4 stores — the HBM-write roofline.
// ---------------------------------------------------------------------------
__global__ __launch_bounds__(256) void k_fill(const int2* __restrict__ rowinfo,
                                              v4f* __restrict__ outc,
                                              v4f* __restrict__ outm) {
    int gid = (blockIdx.x * 256 + threadIdx.x) << 1;  // first of 2 float4s
    int s = gid >> 12;                                // 4096 float4 per row
    int q = (gid & 4095) << 2;                        // float offset in row

    int2 ri = rowinfo[s];
    float v = __int_as_float(ri.y);
    int d = ri.x - q;                                 // nonzero sits at d in [0,8)?

    v4f c0, c1, m0, m1;
    c0.x = (d == 0) ? v : 0.0f;  m0.x = (d == 0) ? 1.0f : 0.0f;
    c0.y = (d == 1) ? v : 0.0f;  m0.y = (d == 1) ? 1.0f : 0.0f;
    c0.z = (d == 2) ? v : 0.0f;  m0.z = (d == 2) ? 1.0f : 0.0f;
    c0.w = (d == 3) ? v : 0.0f;  m0.w = (d == 3) ? 1.0f : 0.0f;
    c1.x = (d == 4) ? v : 0.0f;  m1.x = (d == 4) ? 1.0f : 0.0f;
    c1.y = (d == 5) ? v : 0.0f;  m1.y = (d == 5) ? 1.0f : 0.0f;
    c1.z = (d == 6) ? v : 0.0f;  m1.z = (d == 6) ? 1.0f : 0.0f;
    c1.w = (d == 7) ? v : 0.0f;  m1.w = (d == 7) ? 1.0f : 0.0f;

    __builtin_nontemporal_store(c0, &outc[gid]);
    __builtin_nontemporal_store(c1, &outc[gid + 1]);
    __builtin_nontemporal_store(m0, &outm[gid]);
    __builtin_nontemporal_store(m1, &outm[gid + 1]);
}

extern "C" void kernel_launch(void* const* d_in, const int* in_sizes, int n_in,
                              void* d_out, int out_size, void* d_ws, size_t ws_size,
                              hipStream_t stream) {
    const float* in = (const float*)d_in[0];

    // workspace: top1[8192] int | val[8192] float | rowinfo[8192] int2
    int*   top1    = (int*)d_ws;
    float* val     = (float*)((char*)d_ws + NTOK * 4);
    int2*  rowinfo = (int2*)((char*)d_ws + NTOK * 8);

    float* outc = (float*)d_out;
    float* outm = outc + (size_t)SEC;

    hipLaunchKernelGGL(k_top1, dim3(NTOK / 4), dim3(256), 0, stream, in, top1, val);
    hipLaunchKernelGGL(k_rank, dim3(1), dim3(1024), 0, stream, top1, val, rowinfo);
    hipLaunchKernelGGL(k_fill, dim3(SEC / 4 / 2 / 256), dim3(256), 0, stream,
                       rowinfo, (v4f*)outc, (v4f*)outm);
}

// Round 4
// 1031.469 us; speedup vs baseline: 1.2736x; 1.2736x over previous
//
#include <hip/hip_runtime.h>
#include <math.h>

// Problem constants (S=8192 tokens, E=64 experts, capacity=256)
#define NTOK 8192
#define NEXP 64
#define CAP  256
#define SEC  (NTOK * NEXP * CAP)   // 134217728 floats per output tensor

typedef float v4f __attribute__((ext_vector_type(4)));

// ---------------------------------------------------------------------------
// Kernel 1: per-token argmax (first-index tie-break) + softmax value at top1.
// One wave (64 lanes) per token row; lane e holds logit for expert e.
// ---------------------------------------------------------------------------
__global__ __launch_bounds__(256) void k_top1(const float* __restrict__ in,
                                              int* __restrict__ top1,
                                              float* __restrict__ val) {
    int wave = threadIdx.x >> 6;
    int lane = threadIdx.x & 63;
    int s = blockIdx.x * 4 + wave;
    float x = in[s * NEXP + lane];

    float bv = x;
    int   bi = lane;
#pragma unroll
    for (int off = 32; off > 0; off >>= 1) {
        float ov = __shfl_xor(bv, off);
        int   oi = __shfl_xor(bi, off);
        if (ov > bv || (ov == bv && oi < bi)) { bv = ov; bi = oi; }
    }
    float ex = expf(x - bv);
#pragma unroll
    for (int off = 32; off > 0; off >>= 1) ex += __shfl_xor(ex, off);

    if (lane == 0) {
        top1[s] = bi;
        val[s]  = 1.0f / ex;   // softmax value at the argmax
    }
}

// ---------------------------------------------------------------------------
// Kernel 2: deterministic per-expert exclusive rank via 6-ballot radix masks.
// Single block, 16 waves; wave w owns tokens [w*512, w*512+512).
// Emits packed rowinfo: {pos = t*CAP + rank (or -1 if dropped), bits(val)}.
// ---------------------------------------------------------------------------
__global__ __launch_bounds__(1024) void k_rank(const int* __restrict__ top1,
                                               const float* __restrict__ val,
                                               int2* __restrict__ rowinfo) {
    __shared__ int localrank[NTOK];      // 32 KB
    __shared__ int hist[16][64];
    __shared__ int chunkoff[16][64];

    int tid  = threadIdx.x;
    int w    = tid >> 6;
    int lane = tid & 63;
    int base = w * 512;

    int cnt = 0;  // lane l: tokens so far in this chunk routed to expert l
    for (int j0 = 0; j0 < 512; j0 += 64) {
        int e = top1[base + j0 + lane];
        unsigned long long b0 = __ballot((e & 1)  != 0);
        unsigned long long b1 = __ballot((e & 2)  != 0);
        unsigned long long b2 = __ballot((e & 4)  != 0);
        unsigned long long b3 = __ballot((e & 8)  != 0);
        unsigned long long b4 = __ballot((e & 16) != 0);
        unsigned long long b5 = __ballot((e & 32) != 0);
        unsigned long long my =
            ((e & 1)  ? b0 : ~b0) & ((e & 2)  ? b1 : ~b1) &
            ((e & 4)  ? b2 : ~b2) & ((e & 8)  ? b3 : ~b3) &
            ((e & 16) ? b4 : ~b4) & ((e & 32) ? b5 : ~b5);
        unsigned long long mb =
            ((lane & 1)  ? b0 : ~b0) & ((lane & 2)  ? b1 : ~b1) &
            ((lane & 4)  ? b2 : ~b2) & ((lane & 8)  ? b3 : ~b3) &
            ((lane & 16) ? b4 : ~b4) & ((lane & 32) ? b5 : ~b5);

        int lr  = __popcll(my & ((1ULL << lane) - 1ULL));  // rank within batch
        int off = __shfl(cnt, e);                           // earlier batches, same expert
        localrank[base + j0 + lane] = off + lr;
        cnt += __popcll(mb);
    }
    hist[w][lane] = cnt;
    __syncthreads();

    if (tid < 64) {  // lane-per-expert exclusive scan over 16 chunks
        int off = 0;
        for (int w2 = 0; w2 < 16; ++w2) {
            chunkoff[w2][tid] = off;
            off += hist[w2][tid];
        }
    }
    __syncthreads();

    for (int s = tid; s < NTOK; s += 1024) {
        int t = top1[s];
        int r = localrank[s] + chunkoff[s >> 9][t];
        int pos = (r < CAP) ? (t * CAP + r) : -1;   // -1: dropped token, row all-zero
        rowinfo[s] = make_int2(pos, __float_as_int(val[s]));
    }
}

// ---------------------------------------------------------------------------
// Kernel 3: fused zero-fill + scatter. ONE float4 per output per thread,
// lanes contiguous per store instruction (1 KiB/wave/instr — the R2-proven
// fully-coalesced layout; the 2-per-thread interleave in R3 regressed 2x).
// 1 GiB of nontemporal dwordx4 stores — the HBM-write roofline.
// ---------------------------------------------------------------------------
__global__ __launch_bounds__(256) void k_fill(const int2* __restrict__ rowinfo,
                                              v4f* __restrict__ outc,
                                              v4f* __restrict__ outm) {
    int gid = blockIdx.x * 256 + threadIdx.x;   // float4 index, < SEC/4
    int s = gid >> 12;                          // 4096 float4 per row
    int q = (gid & 4095) << 2;                  // float offset of this float4 in row

    int2 ri = rowinfo[s];                       // wave-uniform → scalar broadcast load
    float v = __int_as_float(ri.y);
    int d = ri.x - q;                           // nonzero at this float4 iff d in [0,4)

    v4f c, m;
    c.x = (d == 0) ? v : 0.0f;  m.x = (d == 0) ? 1.0f : 0.0f;
    c.y = (d == 1) ? v : 0.0f;  m.y = (d == 1) ? 1.0f : 0.0f;
    c.z = (d == 2) ? v : 0.0f;  m.z = (d == 2) ? 1.0f : 0.0f;
    c.w = (d == 3) ? v : 0.0f;  m.w = (d == 3) ? 1.0f : 0.0f;

    __builtin_nontemporal_store(c, &outc[gid]);
    __builtin_nontemporal_store(m, &outm[gid]);
}

extern "C" void kernel_launch(void* const* d_in, const int* in_sizes, int n_in,
                              void* d_out, int out_size, void* d_ws, size_t ws_size,
                              hipStream_t stream) {
    const float* in = (const float*)d_in[0];

    // workspace: top1[8192] int | val[8192] float | rowinfo[8192] int2
    int*   top1    = (int*)d_ws;
    float* val     = (float*)((char*)d_ws + NTOK * 4);
    int2*  rowinfo = (int2*)((char*)d_ws + NTOK * 8);

    float* outc = (float*)d_out;
    float* outm = outc + (size_t)SEC;

    hipLaunchKernelGGL(k_top1, dim3(NTOK / 4), dim3(256), 0, stream, in, top1, val);
    hipLaunchKernelGGL(k_rank, dim3(1), dim3(1024), 0, stream, top1, val, rowinfo);
    hipLaunchKernelGGL(k_fill, dim3(SEC / 4 / 256), dim3(256), 0, stream,
                       rowinfo, (v4f*)outc, (v4f*)outm);
}